// Round 13
// baseline (541.113 us; speedup 1.0000x reference)
//
#include <hip/hip_runtime.h>
#include <hip/hip_bf16.h>
#include <stdint.h>

// Swin window attention, B=32, H=W=56, DIM=512, HEADS=16, HD=32, WS=7, shift=3.
// Round 13: (a) k_qkv MFMA 16x16x32 -> 32x32x16 (fewer, higher-rate matrix ops;
// same staging/swizzle, conflict-free preserved; epilogue uses 32x32 C layout
// col=lane&31, row=(reg&3)+8*(reg>>2)+4*(lane>>5)); (b) all prep kernels merged
// into one launch (prep_x + LUTs + bias + both weight transposes).
// k_attn / k_out unchanged from R12 (best=538us).

#define NWIN 64
#define NTOK 49
#define WIN_ELEMS 1568        // 49*32
#define HEAD_STRIDE 100352    // 64*49*32
#define BATCH_STRIDE 1605632  // 16*64*49*32
#define QKV_ELEMS 51380224    // 32*16*64*49*32
#define NTOKENS 100352
#define SCALE 0.17677669529663687f

typedef __attribute__((ext_vector_type(8))) short bf16x8;
typedef __attribute__((ext_vector_type(4))) float f32x4;
typedef __attribute__((ext_vector_type(16))) float f32x16;

#define AS1 __attribute__((address_space(1)))
#define AS3 __attribute__((address_space(3)))

struct __align__(16) bf8 { __hip_bfloat16 h[8]; };

__device__ __forceinline__ void gload_lds16(const void* g, void* l) {
  __builtin_amdgcn_global_load_lds((const AS1 unsigned int*)g,
                                   (AS3 unsigned int*)l, 16, 0, 0);
}

__device__ __forceinline__ void token_decode(int t, int& b, int& i, int& j) {
  b = t / 3136;
  int r = t - b * 3136;
  i = r / 56;
  j = r - i * 56;
}

__device__ __forceinline__ unsigned pack_bf2(float a, float b) {
  __hip_bfloat16 x = __float2bfloat16(a), y = __float2bfloat16(b);
  unsigned short ux = *(unsigned short*)&x, uy = *(unsigned short*)&y;
  return (unsigned)ux | ((unsigned)uy << 16);
}

// ---------------- merged prep kernel ----------------
// blocks: [0,25088) prep_x | [25088,25480) LUTs | [25480,26504) bias
//         [26504,26696) transpose w_qkv | [26696,26760) transpose w_out
__device__ void do_transpose(const float* __restrict__ in,
                             __hip_bfloat16* __restrict__ out,
                             int K, int N, int nbk, int kbk, int tid) {
  __shared__ float tl[64][65];
  const int nb = nbk * 64, kb = kbk * 64;
#pragma unroll
  for (int s = 0; s < 16; ++s) {
    int idx = s * 256 + tid; int r = idx >> 6, c = idx & 63;
    tl[r][c] = in[(size_t)(kb + r) * N + nb + c];
  }
  __syncthreads();
#pragma unroll
  for (int s = 0; s < 16; ++s) {
    int idx = s * 256 + tid; int r = idx >> 6, c = idx & 63;
    int row = nb + r;
    int col = (kb + c) ^ ((row & 7) << 3);   // producer-side LDS swizzle
    out[(size_t)row * K + col] = __float2bfloat16(tl[c][r]);
  }
}

__global__ __launch_bounds__(256) void k_preps(
    const float* __restrict__ x, const float* __restrict__ w_qkv,
    const float* __restrict__ pe, const float* __restrict__ w_out,
    __hip_bfloat16* __restrict__ xb, __hip_bfloat16* __restrict__ wbt,
    __hip_bfloat16* __restrict__ wot, float* __restrict__ biasT,
    int* __restrict__ lutw, int* __restrict__ luto) {
  const int bid = blockIdx.x, tid = threadIdx.x;
  if (bid < 25088) {
    // ---- P1: x -> bf16, roll(-3,-3), swizzled slot store ----
    int idx = bid * 256 + tid;
    int t = idx >> 6, g = idx & 63;
    int b, i, j;
    token_decode(t, b, i, j);
    int si = i + 3; if (si >= 56) si -= 56;
    int sj = j + 3; if (sj >= 56) sj -= 56;
    const float* src = x + ((size_t)(b * 56 + si) * 56 + sj) * 512 + g * 8;
    float4 a0 = *(const float4*)src;
    float4 a1 = *(const float4*)(src + 4);
    bf8 o;
    o.h[0] = __float2bfloat16(a0.x); o.h[1] = __float2bfloat16(a0.y);
    o.h[2] = __float2bfloat16(a0.z); o.h[3] = __float2bfloat16(a0.w);
    o.h[4] = __float2bfloat16(a1.x); o.h[5] = __float2bfloat16(a1.y);
    o.h[6] = __float2bfloat16(a1.z); o.h[7] = __float2bfloat16(a1.w);
    int slot = ((g * 8) ^ ((t & 7) << 3));
    *(bf8*)(xb + (size_t)t * 512 + slot) = o;
  } else if (bid < 25480) {
    // ---- P0: token offset LUTs ----
    int t = (bid - 25088) * 256 + tid;
    int b, i, j;
    token_decode(t, b, i, j);
    int win = (i / 7) * 8 + (j / 7);
    int pos = (i % 7) * 7 + (j % 7);
    lutw[t] = b * BATCH_STRIDE + win * WIN_ELEMS + pos * 32;
    int di = i + 3; if (di >= 56) di -= 56;
    int dj = j + 3; if (dj >= 56) dj -= 56;
    luto[t] = ((b * 56 + di) * 56 + dj) * 512;
  } else if (bid < 26504) {
    // ---- P4: bias table in 16x16 MFMA fragment layout (used by k_attn) ----
    int id = (bid - 25480) * 256 + tid;
    int whid = id >> 12;
    int wtype = whid >> 4, h = whid & 15;
    int mid = id & 4095;
    int mf = mid >> 10, r = (mid >> 8) & 3, lane = (mid >> 2) & 63, nf = mid & 3;
    int key = mf * 16 + (lane >> 4) * 4 + r;
    int query = nf * 16 + (lane & 15);
    float v;
    if (key >= 49 || query >= 49) {
      v = -1e30f;
    } else {
      int i = query, j = key;
      int xi = i / 7, yi = i - xi * 7;
      int xj = j / 7, yj = j - xj * 7;
      int dx = xj - xi; if (dx < 0) dx += 13;
      int dy = yj - yi; if (dy < 0) dy += 13;
      v = pe[(dx * 13 + dy) * 16 + h];
      if ((wtype & 1) && ((xi >= 4) != (xj >= 4))) v = -1e30f;
      if ((wtype & 2) && ((yi >= 4) != (yj >= 4))) v = -1e30f;
    }
    biasT[id] = v;
  } else if (bid < 26696) {
    int id = bid - 26504;                    // 24 x 8
    do_transpose(w_qkv, wbt, 512, 1536, id % 24, id / 24, tid);
  } else {
    int id = bid - 26696;                    // 8 x 8
    do_transpose(w_out, wot, 512, 512, id % 8, id / 8, tid);
  }
}

// ---------------- K1: QKV GEMM, bf16 MFMA 32x32x16, counted-vmcnt (R8 skeleton) ----------------
// M=100352, N=1536, K=512. 128x128 tile, BK=64, 4 waves (2x2), 64x64 per wave.
__global__ __launch_bounds__(256) void k_qkv_mfma(
    const __hip_bfloat16* __restrict__ xb, const __hip_bfloat16* __restrict__ wbt,
    const int* __restrict__ lutw,
    __hip_bfloat16* __restrict__ qb, __hip_bfloat16* __restrict__ kb,
    __hip_bfloat16* __restrict__ vb) {
  __shared__ __align__(16) short As[2][128 * 64];
  __shared__ __align__(16) short Bs[2][128 * 64];
  const int tid = threadIdx.x;
  const int lid = blockIdx.x;                 // 9408 blocks
  const int wid = (lid & 7) * 1176 + (lid >> 3);
  const int t0 = (wid / 12) * 128;
  const int n0 = (wid % 12) * 128;
  const int lane = tid & 63, wave = tid >> 6;
  const int wm = wave >> 1, wn = wave & 1;

  const __hip_bfloat16* asrc[4];
  const __hip_bfloat16* bsrc[4];
#pragma unroll
  for (int s = 0; s < 4; ++s) {
    int c = s * 256 + tid;
    int row = c >> 3, kc = c & 7;
    asrc[s] = xb + (size_t)(t0 + row) * 512 + kc * 8;
    bsrc[s] = wbt + (size_t)(n0 + row) * 512 + kc * 8;
  }

  f32x16 acc[2][2] = {};
  const int r32 = lane & 31;
  const int arow = wm * 64 + r32;             // + mb*32
  const int brow = wn * 64 + r32;             // + nb*32
  const int kq = (lane >> 5) * 8;             // k-elem offset within k-slice
  const int sw = (lane & 7) << 3;             // producer swizzle involution

  // prologue: stage K-tile 0 into buf 0 (8 loads/thread)
#pragma unroll
  for (int s = 0; s < 4; ++s) {
    gload_lds16(asrc[s], (char*)As[0] + wave * 1024 + s * 4096);
    gload_lds16(bsrc[s], (char*)Bs[0] + wave * 1024 + s * 4096);
  }

  for (int t = 0; t < 8; ++t) {
    const int buf = t & 1;
    if (t < 7) {
      const int kt = (t + 1) * 64;
#pragma unroll
      for (int s = 0; s < 4; ++s) {
        gload_lds16(asrc[s] + kt, (char*)As[buf ^ 1] + wave * 1024 + s * 4096);
        gload_lds16(bsrc[s] + kt, (char*)Bs[buf ^ 1] + wave * 1024 + s * 4096);
      }
      asm volatile("s_waitcnt vmcnt(8)" ::: "memory");
    } else {
      asm volatile("s_waitcnt vmcnt(0)" ::: "memory");
    }
    __builtin_amdgcn_s_barrier();
    __builtin_amdgcn_sched_barrier(0);

    bf16x8 af[2][4], bfr[2][4];               // [m/n 32-block][k-slice]
#pragma unroll
    for (int ks = 0; ks < 4; ++ks) {
      const int eo = (ks * 16 + kq) ^ sw;
      af[0][ks] = *(const bf16x8*)&As[buf][arow * 64 + eo];
      af[1][ks] = *(const bf16x8*)&As[buf][(arow + 32) * 64 + eo];
      bfr[0][ks] = *(const bf16x8*)&Bs[buf][brow * 64 + eo];
      bfr[1][ks] = *(const bf16x8*)&Bs[buf][(brow + 32) * 64 + eo];
    }
    __builtin_amdgcn_s_setprio(1);
#pragma unroll
    for (int ks = 0; ks < 4; ++ks)
#pragma unroll
      for (int mb = 0; mb < 2; ++mb)
#pragma unroll
        for (int nb = 0; nb < 2; ++nb)
          acc[mb][nb] = __builtin_amdgcn_mfma_f32_32x32x16_bf16(
              af[mb][ks], bfr[nb][ks], acc[mb][nb], 0, 0, 0);
    __builtin_amdgcn_s_setprio(0);
    __builtin_amdgcn_s_barrier();
    __builtin_amdgcn_sched_barrier(0);
  }

  // epilogue (32x32 C layout: col=lane&31, row=(reg&3)+8*(reg>>2)+4*(lane>>5))
  __hip_bfloat16* obs[2];
#pragma unroll
  for (int nb = 0; nb < 2; ++nb) {
    int n = n0 + wn * 64 + nb * 32;
    int sp = n >> 9, hc = n & 511, h = hc >> 5;
    obs[nb] = (sp == 0 ? qb : (sp == 1 ? kb : vb)) + (size_t)h * HEAD_STRIDE + r32;
  }
  const int rbase = t0 + wm * 64 + (lane >> 5) * 4;
#pragma unroll
  for (int mb = 0; mb < 2; ++mb)
#pragma unroll
    for (int rg = 0; rg < 4; ++rg)
#pragma unroll
      for (int rr = 0; rr < 4; ++rr) {
        int trow = rbase + mb * 32 + rg * 8 + rr;
        size_t off = (size_t)lutw[trow];
#pragma unroll
        for (int nb = 0; nb < 2; ++nb)
          obs[nb][off] = __float2bfloat16(acc[mb][nb][rg * 4 + rr]);
      }
}

// ---------------- K2: attention via MFMA, one wave per (b,h,win) (R12) ----------------
__global__ __launch_bounds__(256) void k_attn_mfma(
    const __hip_bfloat16* __restrict__ qb, const __hip_bfloat16* __restrict__ kb,
    const __hip_bfloat16* __restrict__ vb, const float* __restrict__ biasT,
    __hip_bfloat16* __restrict__ ab) {
  __shared__ __align__(16) __hip_bfloat16 P[4][64 * 72];   // per-wave P[query][key]
  const int tid = threadIdx.x, lane = tid & 63, wave = tid >> 6;
  const int gid = blockIdx.x * 4 + wave;                   // (b*16+h)*64 + win
  const int win = gid & 63, h = (gid >> 6) & 15;
  const int wtype = (((win >> 3) == 7) ? 1 : 0) | (((win & 7) == 7) ? 2 : 0);
  const size_t qkbase = (size_t)gid * WIN_ELEMS;
  const int fr = lane & 15, fo = (lane >> 4) * 8;

  // V fragments direct from global, hoisted early to hide latency.
  bf16x8 vfr[2][2];
  const short* vbs = (const short*)(vb + qkbase);
#pragma unroll
  for (int kk = 0; kk < 2; ++kk)
#pragma unroll
    for (int n2 = 0; n2 < 2; ++n2) {
      const short* vp = vbs + (kk * 32 + fo) * 32 + n2 * 16 + fr;
#pragma unroll
      for (int j = 0; j < 8; ++j) vfr[kk][n2][j] = vp[j * 32];
    }

  // Q,K fragments straight from global ([tok][d32], d==K of MFMA)
  bf16x8 kf[4], qf[4];
#pragma unroll
  for (int f = 0; f < 4; ++f) {
    kf[f] = *(const bf16x8*)(kb + qkbase + (size_t)(f * 16 + fr) * 32 + fo);
    qf[f] = *(const bf16x8*)(qb + qkbase + (size_t)(f * 16 + fr) * 32 + fo);
  }

  // S^T[key][query] = K @ Q^T
  f32x4 sacc[4][4] = {};
  __builtin_amdgcn_s_setprio(1);
#pragma unroll
  for (int mf = 0; mf < 4; ++mf)
#pragma unroll
    for (int nf = 0; nf < 4; ++nf)
      sacc[mf][nf] = __builtin_amdgcn_mfma_f32_16x16x32_bf16(
          kf[mf], qf[nf], sacc[mf][nf], 0, 0, 0);
  __builtin_amdgcn_s_setprio(0);

  // scale + bias/mask table (fragment-layout, coalesced float4)
  const float* bp = biasT + (size_t)(wtype * 16 + h) * 4096;
#pragma unroll
  for (int mf = 0; mf < 4; ++mf)
#pragma unroll
    for (int r = 0; r < 4; ++r) {
      float4 bv = *(const float4*)(bp + ((mf * 4 + r) * 64 + lane) * 4);
      sacc[mf][0][r] = fmaf(sacc[mf][0][r], SCALE, bv.x);
      sacc[mf][1][r] = fmaf(sacc[mf][1][r], SCALE, bv.y);
      sacc[mf][2][r] = fmaf(sacc[mf][2][r], SCALE, bv.z);
      sacc[mf][3][r] = fmaf(sacc[mf][3][r], SCALE, bv.w);
    }

  // softmax over keys (rows of S^T): per query col, 16 local + 2 shuffles
  float inv[4];
#pragma unroll
  for (int nf = 0; nf < 4; ++nf) {
    float m = sacc[0][nf][0];
#pragma unroll
    for (int mf = 0; mf < 4; ++mf)
#pragma unroll
      for (int r = 0; r < 4; ++r) m = fmaxf(m, sacc[mf][nf][r]);
    m = fmaxf(m, __shfl_xor(m, 16));
    m = fmaxf(m, __shfl_xor(m, 32));
    float sum = 0.f;
#pragma unroll
    for (int mf = 0; mf < 4; ++mf)
#pragma unroll
      for (int r = 0; r < 4; ++r) {
        float e = __expf(sacc[mf][nf][r] - m);
        sacc[mf][nf][r] = e;
        sum += e;
      }
    sum += __shfl_xor(sum, 16);
    sum += __shfl_xor(sum, 32);
    inv[nf] = 1.0f / sum;
  }

  // write P[query][key] (bf16, key-pairs packed to b32), transposed for PV A-op
  __hip_bfloat16* pw = P[wave];
#pragma unroll
  for (int mf = 0; mf < 4; ++mf)
#pragma unroll
    for (int r = 0; r < 4; r += 2) {
      int key = mf * 16 + (lane >> 4) * 4 + r;
#pragma unroll
      for (int nf = 0; nf < 4; ++nf) {
        int query = nf * 16 + fr;
        *(unsigned*)&pw[query * 72 + key] =
            pack_bf2(sacc[mf][nf][r] * inv[nf], sacc[mf][nf][r + 1] * inv[nf]);
      }
    }

  // O = P @ V via MFMA; V from pre-gathered registers
  f32x4 oacc[4][2] = {};
#pragma unroll
  for (int kk = 0; kk < 2; ++kk) {
    __builtin_amdgcn_s_setprio(1);
#pragma unroll
    for (int mf = 0; mf < 4; ++mf) {
      bf16x8 pa = *(const bf16x8*)&pw[(mf * 16 + fr) * 72 + kk * 32 + fo];
#pragma unroll
      for (int n2 = 0; n2 < 2; ++n2)
        oacc[mf][n2] = __builtin_amdgcn_mfma_f32_16x16x32_bf16(
            pa, vfr[kk][n2], oacc[mf][n2], 0, 0, 0);
    }
    __builtin_amdgcn_s_setprio(0);
  }

  // store O rows < 49 to windowed [tok49][d32]
#pragma unroll
  for (int mf = 0; mf < 4; ++mf)
#pragma unroll
    for (int r = 0; r < 4; ++r) {
      int row = mf * 16 + (lane >> 4) * 4 + r;
      if (row < 49) {
#pragma unroll
        for (int n2 = 0; n2 < 2; ++n2)
          ab[qkbase + (size_t)row * 32 + n2 * 16 + fr] =
              __float2bfloat16(oacc[mf][n2][r]);
      }
    }
}

// ---------------- K3: output GEMM, bf16 MFMA, counted-vmcnt pipeline (R8) ----------------
__global__ __launch_bounds__(256) void k_out_mfma(
    const __hip_bfloat16* __restrict__ ab, const __hip_bfloat16* __restrict__ wot,
    const int* __restrict__ lutw, const int* __restrict__ luto,
    const float* __restrict__ bias, float* __restrict__ out) {
  __shared__ __align__(16) short As[2][128 * 64];
  __shared__ __align__(16) short Bs[2][128 * 64];
  const int tid = threadIdx.x;
  const int lid = blockIdx.x;                 // 3136 blocks
  const int wid = (lid & 7) * 392 + (lid >> 3);
  const int t0 = (wid >> 2) * 128;
  const int n0 = (wid & 3) * 128;
  const int lane = tid & 63, wave = tid >> 6;
  const int wm = wave >> 1, wn = wave & 1;

  size_t aoff[4];
  const __hip_bfloat16* bsrc[4];
#pragma unroll
  for (int s = 0; s < 4; ++s) {
    int c = s * 256 + tid;
    int row = c >> 3, kc = c & 7;
    aoff[s] = (size_t)lutw[t0 + row] + (size_t)(kc >> 2) * HEAD_STRIDE + (kc & 3) * 8;
    bsrc[s] = wot + (size_t)(n0 + row) * 512 + kc * 8;
  }

  f32x4 acc[4][4] = {};
  const int arow = wm * 64 + (lane & 15);
  const int brow = wn * 64 + (lane & 15);
  const int koff = (lane >> 4) * 8;
  const int sw = (lane & 7) << 3;

  // prologue: stage K-tile 0 into buf 0
#pragma unroll
  for (int s = 0; s < 4; ++s) {
    gload_lds16(ab + aoff[s], (char*)As[0] + wave * 1024 + s * 4096);
    gload_lds16(bsrc[s], (char*)Bs[0] + wave * 1024 + s * 4096);
  }

  for (int t = 0; t < 8; ++t) {
    const int buf = t & 1;
    if (t < 7) {
      const int kt = (t + 1) * 64;
      size_t hoff = (size_t)(kt >> 5) * HEAD_STRIDE;
#pragma unroll
      for (int s = 0; s < 4; ++s) {
        gload_lds16(ab + aoff[s] + hoff, (char*)As[buf ^ 1] + wave * 1024 + s * 4096);
        gload_lds16(bsrc[s] + kt, (char*)Bs[buf ^ 1] + wave * 1024 + s * 4096);
      }
      asm volatile("s_waitcnt vmcnt(8)" ::: "memory");
    } else {
      asm volatile("s_waitcnt vmcnt(0)" ::: "memory");
    }
    __builtin_amdgcn_s_barrier();
    __builtin_amdgcn_sched_barrier(0);

    bf16x8 af[2][4], bfr[2][4];
#pragma unroll
    for (int kk = 0; kk < 2; ++kk) {
      const int eo = kk * 32 + koff;
#pragma unroll
      for (int mf = 0; mf < 4; ++mf)
        af[kk][mf] = *(const bf16x8*)&As[buf][(arow + mf * 16) * 64 + eo];
#pragma unroll
      for (int nf = 0; nf < 4; ++nf)
        bfr[kk][nf] = *(const bf16x8*)&Bs[buf][(brow + nf * 16) * 64 + (eo ^ sw)];
    }
    __builtin_amdgcn_s_setprio(1);
#pragma unroll
    for (int kk = 0; kk < 2; ++kk)
#pragma unroll
      for (int mf = 0; mf < 4; ++mf)
#pragma unroll
        for (int nf = 0; nf < 4; ++nf)
          acc[mf][nf] = __builtin_amdgcn_mfma_f32_16x16x32_bf16(
              af[kk][mf], bfr[kk][nf], acc[mf][nf], 0, 0, 0);
    __builtin_amdgcn_s_setprio(0);
    __builtin_amdgcn_s_barrier();
    __builtin_amdgcn_sched_barrier(0);
  }

  float bia[4];
#pragma unroll
  for (int nf = 0; nf < 4; ++nf)
    bia[nf] = bias[n0 + wn * 64 + nf * 16 + (lane & 15)];

  const int tbase = t0 + wm * 64 + (lane >> 4) * 4;
  int ooff[4][4];
#pragma unroll
  for (int mf = 0; mf < 4; ++mf)
#pragma unroll
    for (int r = 0; r < 4; ++r)
      ooff[mf][r] = luto[tbase + mf * 16 + r];
#pragma unroll
  for (int mf = 0; mf < 4; ++mf) {
#pragma unroll
    for (int r = 0; r < 4; ++r) {
      float* op = out + (size_t)ooff[mf][r] + n0 + wn * 64 + (lane & 15);
#pragma unroll
      for (int nf = 0; nf < 4; ++nf) op[nf * 16] = acc[mf][nf][r] + bia[nf];
    }
  }
}

extern "C" void kernel_launch(void* const* d_in, const int* in_sizes, int n_in,
                              void* d_out, int out_size, void* d_ws, size_t ws_size,
                              hipStream_t stream) {
  const float* x     = (const float*)d_in[0];
  const float* w_qkv = (const float*)d_in[1];
  const float* pe    = (const float*)d_in[2];
  const float* w_out = (const float*)d_in[3];
  const float* b_out = (const float*)d_in[4];
  float* out = (float*)d_out;

  __hip_bfloat16* qb  = (__hip_bfloat16*)d_ws;          // 51,380,224
  __hip_bfloat16* kb  = qb + (size_t)QKV_ELEMS;         // 51,380,224
  __hip_bfloat16* vb  = kb + (size_t)QKV_ELEMS;         // 51,380,224
  __hip_bfloat16* xb  = vb + (size_t)QKV_ELEMS;         // 51,380,224 (aliased ab)
  __hip_bfloat16* ab  = xb;
  __hip_bfloat16* wbt = xb + (size_t)QKV_ELEMS;         // 786,432
  __hip_bfloat16* wot = wbt + (size_t)(1536 * 512);     // 262,144
  float* biasT = (float*)(wot + (size_t)(512 * 512));   // 262,144 f32 (1 MB)
  int* lutw = (int*)(biasT + 262144);                   // 100,352 int
  int* luto = lutw + NTOKENS;                           // 100,352 int

  k_preps<<<dim3(26760), dim3(256), 0, stream>>>(x, w_qkv, pe, w_out,
                                                 xb, wbt, wot, biasT, lutw, luto);
  k_qkv_mfma<<<dim3(9408), dim3(256), 0, stream>>>(xb, wbt, lutw, qb, kb, vb);
  k_attn_mfma<<<dim3(8192), dim3(256), 0, stream>>>(qb, kb, vb, biasT, ab);
  k_out_mfma<<<dim3(3136), dim3(256), 0, stream>>>(ab, wot, lutw, luto, b_out, out);
}

// Round 14
// 526.771 us; speedup vs baseline: 1.0272x; 1.0272x over previous
//
#include <hip/hip_runtime.h>
#include <hip/hip_bf16.h>
#include <stdint.h>

// Swin window attention, B=32, H=W=56, DIM=512, HEADS=16, HD=32, WS=7, shift=3.
// Round 14: recombine the proven-best pieces — R12's kernels (k_qkv 16x16x32
// counted-vmcnt, conflict-free; k_attn V-direct; k_out R8 pipeline) + R13's
// single merged prep launch. No new structural experiments.

#define NWIN 64
#define NTOK 49
#define WIN_ELEMS 1568        // 49*32
#define HEAD_STRIDE 100352    // 64*49*32
#define BATCH_STRIDE 1605632  // 16*64*49*32
#define QKV_ELEMS 51380224    // 32*16*64*49*32
#define NTOKENS 100352
#define SCALE 0.17677669529663687f

typedef __attribute__((ext_vector_type(8))) short bf16x8;
typedef __attribute__((ext_vector_type(4))) float f32x4;

#define AS1 __attribute__((address_space(1)))
#define AS3 __attribute__((address_space(3)))

struct __align__(16) bf8 { __hip_bfloat16 h[8]; };

__device__ __forceinline__ void gload_lds16(const void* g, void* l) {
  __builtin_amdgcn_global_load_lds((const AS1 unsigned int*)g,
                                   (AS3 unsigned int*)l, 16, 0, 0);
}

__device__ __forceinline__ void token_decode(int t, int& b, int& i, int& j) {
  b = t / 3136;
  int r = t - b * 3136;
  i = r / 56;
  j = r - i * 56;
}

__device__ __forceinline__ unsigned pack_bf2(float a, float b) {
  __hip_bfloat16 x = __float2bfloat16(a), y = __float2bfloat16(b);
  unsigned short ux = *(unsigned short*)&x, uy = *(unsigned short*)&y;
  return (unsigned)ux | ((unsigned)uy << 16);
}

// ---------------- merged prep kernel ----------------
// blocks: [0,25088) prep_x | [25088,25480) LUTs | [25480,26504) bias
//         [26504,26696) transpose w_qkv | [26696,26760) transpose w_out
__device__ void do_transpose(const float* __restrict__ in,
                             __hip_bfloat16* __restrict__ out,
                             int K, int N, int nbk, int kbk, int tid) {
  __shared__ float tl[64][65];
  const int nb = nbk * 64, kb = kbk * 64;
#pragma unroll
  for (int s = 0; s < 16; ++s) {
    int idx = s * 256 + tid; int r = idx >> 6, c = idx & 63;
    tl[r][c] = in[(size_t)(kb + r) * N + nb + c];
  }
  __syncthreads();
#pragma unroll
  for (int s = 0; s < 16; ++s) {
    int idx = s * 256 + tid; int r = idx >> 6, c = idx & 63;
    int row = nb + r;
    int col = (kb + c) ^ ((row & 7) << 3);   // producer-side LDS swizzle
    out[(size_t)row * K + col] = __float2bfloat16(tl[c][r]);
  }
}

__global__ __launch_bounds__(256) void k_preps(
    const float* __restrict__ x, const float* __restrict__ w_qkv,
    const float* __restrict__ pe, const float* __restrict__ w_out,
    __hip_bfloat16* __restrict__ xb, __hip_bfloat16* __restrict__ wbt,
    __hip_bfloat16* __restrict__ wot, float* __restrict__ biasT,
    int* __restrict__ lutw, int* __restrict__ luto) {
  const int bid = blockIdx.x, tid = threadIdx.x;
  if (bid < 25088) {
    // ---- P1: x -> bf16, roll(-3,-3), swizzled slot store ----
    int idx = bid * 256 + tid;
    int t = idx >> 6, g = idx & 63;
    int b, i, j;
    token_decode(t, b, i, j);
    int si = i + 3; if (si >= 56) si -= 56;
    int sj = j + 3; if (sj >= 56) sj -= 56;
    const float* src = x + ((size_t)(b * 56 + si) * 56 + sj) * 512 + g * 8;
    float4 a0 = *(const float4*)src;
    float4 a1 = *(const float4*)(src + 4);
    bf8 o;
    o.h[0] = __float2bfloat16(a0.x); o.h[1] = __float2bfloat16(a0.y);
    o.h[2] = __float2bfloat16(a0.z); o.h[3] = __float2bfloat16(a0.w);
    o.h[4] = __float2bfloat16(a1.x); o.h[5] = __float2bfloat16(a1.y);
    o.h[6] = __float2bfloat16(a1.z); o.h[7] = __float2bfloat16(a1.w);
    int slot = ((g * 8) ^ ((t & 7) << 3));
    *(bf8*)(xb + (size_t)t * 512 + slot) = o;
  } else if (bid < 25480) {
    // ---- P0: token offset LUTs ----
    int t = (bid - 25088) * 256 + tid;
    int b, i, j;
    token_decode(t, b, i, j);
    int win = (i / 7) * 8 + (j / 7);
    int pos = (i % 7) * 7 + (j % 7);
    lutw[t] = b * BATCH_STRIDE + win * WIN_ELEMS + pos * 32;
    int di = i + 3; if (di >= 56) di -= 56;
    int dj = j + 3; if (dj >= 56) dj -= 56;
    luto[t] = ((b * 56 + di) * 56 + dj) * 512;
  } else if (bid < 26504) {
    // ---- P4: bias table in 16x16 MFMA fragment layout ----
    int id = (bid - 25480) * 256 + tid;
    int whid = id >> 12;
    int wtype = whid >> 4, h = whid & 15;
    int mid = id & 4095;
    int mf = mid >> 10, r = (mid >> 8) & 3, lane = (mid >> 2) & 63, nf = mid & 3;
    int key = mf * 16 + (lane >> 4) * 4 + r;
    int query = nf * 16 + (lane & 15);
    float v;
    if (key >= 49 || query >= 49) {
      v = -1e30f;
    } else {
      int i = query, j = key;
      int xi = i / 7, yi = i - xi * 7;
      int xj = j / 7, yj = j - xj * 7;
      int dx = xj - xi; if (dx < 0) dx += 13;
      int dy = yj - yi; if (dy < 0) dy += 13;
      v = pe[(dx * 13 + dy) * 16 + h];
      if ((wtype & 1) && ((xi >= 4) != (xj >= 4))) v = -1e30f;
      if ((wtype & 2) && ((yi >= 4) != (yj >= 4))) v = -1e30f;
    }
    biasT[id] = v;
  } else if (bid < 26696) {
    int id = bid - 26504;                    // 24 x 8
    do_transpose(w_qkv, wbt, 512, 1536, id % 24, id / 24, tid);
  } else {
    int id = bid - 26696;                    // 8 x 8
    do_transpose(w_out, wot, 512, 512, id % 8, id / 8, tid);
  }
}

// ---------------- K1: QKV GEMM, bf16 MFMA 16x16x32, counted-vmcnt (R8/R12) ----------------
__global__ __launch_bounds__(256) void k_qkv_mfma(
    const __hip_bfloat16* __restrict__ xb, const __hip_bfloat16* __restrict__ wbt,
    const int* __restrict__ lutw,
    __hip_bfloat16* __restrict__ qb, __hip_bfloat16* __restrict__ kb,
    __hip_bfloat16* __restrict__ vb) {
  __shared__ __align__(16) short As[2][128 * 64];
  __shared__ __align__(16) short Bs[2][128 * 64];
  const int tid = threadIdx.x;
  const int lid = blockIdx.x;                 // 9408 blocks
  const int wid = (lid & 7) * 1176 + (lid >> 3);
  const int t0 = (wid / 12) * 128;
  const int n0 = (wid % 12) * 128;
  const int lane = tid & 63, wave = tid >> 6;
  const int wm = wave >> 1, wn = wave & 1;

  const __hip_bfloat16* asrc[4];
  const __hip_bfloat16* bsrc[4];
#pragma unroll
  for (int s = 0; s < 4; ++s) {
    int c = s * 256 + tid;
    int row = c >> 3, kc = c & 7;
    asrc[s] = xb + (size_t)(t0 + row) * 512 + kc * 8;
    bsrc[s] = wbt + (size_t)(n0 + row) * 512 + kc * 8;
  }

  f32x4 acc[4][4] = {};
  const int arow = wm * 64 + (lane & 15);
  const int brow = wn * 64 + (lane & 15);
  const int koff = (lane >> 4) * 8;
  const int sw = (lane & 7) << 3;

  // prologue: stage K-tile 0 into buf 0 (8 loads/thread)
#pragma unroll
  for (int s = 0; s < 4; ++s) {
    gload_lds16(asrc[s], (char*)As[0] + wave * 1024 + s * 4096);
    gload_lds16(bsrc[s], (char*)Bs[0] + wave * 1024 + s * 4096);
  }

  for (int t = 0; t < 8; ++t) {
    const int buf = t & 1;
    if (t < 7) {
      const int kt = (t + 1) * 64;
#pragma unroll
      for (int s = 0; s < 4; ++s) {
        gload_lds16(asrc[s] + kt, (char*)As[buf ^ 1] + wave * 1024 + s * 4096);
        gload_lds16(bsrc[s] + kt, (char*)Bs[buf ^ 1] + wave * 1024 + s * 4096);
      }
      asm volatile("s_waitcnt vmcnt(8)" ::: "memory");
    } else {
      asm volatile("s_waitcnt vmcnt(0)" ::: "memory");
    }
    __builtin_amdgcn_s_barrier();
    __builtin_amdgcn_sched_barrier(0);

    bf16x8 af[2][4], bfr[2][4];
#pragma unroll
    for (int kk = 0; kk < 2; ++kk) {
      const int eo = (kk * 32 + koff) ^ sw;
#pragma unroll
      for (int mf = 0; mf < 4; ++mf)
        af[kk][mf] = *(const bf16x8*)&As[buf][(arow + mf * 16) * 64 + eo];
#pragma unroll
      for (int nf = 0; nf < 4; ++nf)
        bfr[kk][nf] = *(const bf16x8*)&Bs[buf][(brow + nf * 16) * 64 + eo];
    }
    __builtin_amdgcn_s_setprio(1);
#pragma unroll
    for (int kk = 0; kk < 2; ++kk)
#pragma unroll
      for (int mf = 0; mf < 4; ++mf)
#pragma unroll
        for (int nf = 0; nf < 4; ++nf)
          acc[mf][nf] = __builtin_amdgcn_mfma_f32_16x16x32_bf16(
              af[kk][mf], bfr[kk][nf], acc[mf][nf], 0, 0, 0);
    __builtin_amdgcn_s_setprio(0);
    __builtin_amdgcn_s_barrier();
    __builtin_amdgcn_sched_barrier(0);
  }

  // epilogue: q/k/v -> windowed [b][h][win][pos49][d32]; offsets via LUT
  __hip_bfloat16* obs[4];
#pragma unroll
  for (int nf = 0; nf < 4; ++nf) {
    int n = n0 + wn * 64 + nf * 16 + (lane & 15);
    int sp = n >> 9, hc = n & 511, h = hc >> 5, d = hc & 31;
    obs[nf] = (sp == 0 ? qb : (sp == 1 ? kb : vb)) + (size_t)h * HEAD_STRIDE + d;
  }
  const int tbase = t0 + wm * 64 + (lane >> 4) * 4;
  int woff[4][4];
#pragma unroll
  for (int mf = 0; mf < 4; ++mf)
#pragma unroll
    for (int r = 0; r < 4; ++r)
      woff[mf][r] = lutw[tbase + mf * 16 + r];
#pragma unroll
  for (int mf = 0; mf < 4; ++mf)
#pragma unroll
    for (int r = 0; r < 4; ++r) {
      size_t off = (size_t)woff[mf][r];
#pragma unroll
      for (int nf = 0; nf < 4; ++nf)
        obs[nf][off] = __float2bfloat16(acc[mf][nf][r]);
    }
}

// ---------------- K2: attention via MFMA, one wave per (b,h,win) (R12) ----------------
__global__ __launch_bounds__(256) void k_attn_mfma(
    const __hip_bfloat16* __restrict__ qb, const __hip_bfloat16* __restrict__ kb,
    const __hip_bfloat16* __restrict__ vb, const float* __restrict__ biasT,
    __hip_bfloat16* __restrict__ ab) {
  __shared__ __align__(16) __hip_bfloat16 P[4][64 * 72];   // per-wave P[query][key]
  const int tid = threadIdx.x, lane = tid & 63, wave = tid >> 6;
  const int gid = blockIdx.x * 4 + wave;                   // (b*16+h)*64 + win
  const int win = gid & 63, h = (gid >> 6) & 15;
  const int wtype = (((win >> 3) == 7) ? 1 : 0) | (((win & 7) == 7) ? 2 : 0);
  const size_t qkbase = (size_t)gid * WIN_ELEMS;
  const int fr = lane & 15, fo = (lane >> 4) * 8;

  // V fragments direct from global, hoisted early to hide latency.
  bf16x8 vfr[2][2];
  const short* vbs = (const short*)(vb + qkbase);
#pragma unroll
  for (int kk = 0; kk < 2; ++kk)
#pragma unroll
    for (int n2 = 0; n2 < 2; ++n2) {
      const short* vp = vbs + (kk * 32 + fo) * 32 + n2 * 16 + fr;
#pragma unroll
      for (int j = 0; j < 8; ++j) vfr[kk][n2][j] = vp[j * 32];
    }

  // Q,K fragments straight from global ([tok][d32], d==K of MFMA)
  bf16x8 kf[4], qf[4];
#pragma unroll
  for (int f = 0; f < 4; ++f) {
    kf[f] = *(const bf16x8*)(kb + qkbase + (size_t)(f * 16 + fr) * 32 + fo);
    qf[f] = *(const bf16x8*)(qb + qkbase + (size_t)(f * 16 + fr) * 32 + fo);
  }

  // S^T[key][query] = K @ Q^T
  f32x4 sacc[4][4] = {};
  __builtin_amdgcn_s_setprio(1);
#pragma unroll
  for (int mf = 0; mf < 4; ++mf)
#pragma unroll
    for (int nf = 0; nf < 4; ++nf)
      sacc[mf][nf] = __builtin_amdgcn_mfma_f32_16x16x32_bf16(
          kf[mf], qf[nf], sacc[mf][nf], 0, 0, 0);
  __builtin_amdgcn_s_setprio(0);

  // scale + bias/mask table (fragment-layout, coalesced float4)
  const float* bp = biasT + (size_t)(wtype * 16 + h) * 4096;
#pragma unroll
  for (int mf = 0; mf < 4; ++mf)
#pragma unroll
    for (int r = 0; r < 4; ++r) {
      float4 bv = *(const float4*)(bp + ((mf * 4 + r) * 64 + lane) * 4);
      sacc[mf][0][r] = fmaf(sacc[mf][0][r], SCALE, bv.x);
      sacc[mf][1][r] = fmaf(sacc[mf][1][r], SCALE, bv.y);
      sacc[mf][2][r] = fmaf(sacc[mf][2][r], SCALE, bv.z);
      sacc[mf][3][r] = fmaf(sacc[mf][3][r], SCALE, bv.w);
    }

  // softmax over keys (rows of S^T): per query col, 16 local + 2 shuffles
  float inv[4];
#pragma unroll
  for (int nf = 0; nf < 4; ++nf) {
    float m = sacc[0][nf][0];
#pragma unroll
    for (int mf = 0; mf < 4; ++mf)
#pragma unroll
      for (int r = 0; r < 4; ++r) m = fmaxf(m, sacc[mf][nf][r]);
    m = fmaxf(m, __shfl_xor(m, 16));
    m = fmaxf(m, __shfl_xor(m, 32));
    float sum = 0.f;
#pragma unroll
    for (int mf = 0; mf < 4; ++mf)
#pragma unroll
      for (int r = 0; r < 4; ++r) {
        float e = __expf(sacc[mf][nf][r] - m);
        sacc[mf][nf][r] = e;
        sum += e;
      }
    sum += __shfl_xor(sum, 16);
    sum += __shfl_xor(sum, 32);
    inv[nf] = 1.0f / sum;
  }

  // write P[query][key] (bf16, key-pairs packed to b32), transposed for PV A-op
  __hip_bfloat16* pw = P[wave];
#pragma unroll
  for (int mf = 0; mf < 4; ++mf)
#pragma unroll
    for (int r = 0; r < 4; r += 2) {
      int key = mf * 16 + (lane >> 4) * 4 + r;
#pragma unroll
      for (int nf = 0; nf < 4; ++nf) {
        int query = nf * 16 + fr;
        *(unsigned*)&pw[query * 72 + key] =
            pack_bf2(sacc[mf][nf][r] * inv[nf], sacc[mf][nf][r + 1] * inv[nf]);
      }
    }

  // O = P @ V via MFMA; V from pre-gathered registers
  f32x4 oacc[4][2] = {};
#pragma unroll
  for (int kk = 0; kk < 2; ++kk) {
    __builtin_amdgcn_s_setprio(1);
#pragma unroll
    for (int mf = 0; mf < 4; ++mf) {
      bf16x8 pa = *(const bf16x8*)&pw[(mf * 16 + fr) * 72 + kk * 32 + fo];
#pragma unroll
      for (int n2 = 0; n2 < 2; ++n2)
        oacc[mf][n2] = __builtin_amdgcn_mfma_f32_16x16x32_bf16(
            pa, vfr[kk][n2], oacc[mf][n2], 0, 0, 0);
    }
    __builtin_amdgcn_s_setprio(0);
  }

  // store O rows < 49 to windowed [tok49][d32]
#pragma unroll
  for (int mf = 0; mf < 4; ++mf)
#pragma unroll
    for (int r = 0; r < 4; ++r) {
      int row = mf * 16 + (lane >> 4) * 4 + r;
      if (row < 49) {
#pragma unroll
        for (int n2 = 0; n2 < 2; ++n2)
          ab[qkbase + (size_t)row * 32 + n2 * 16 + fr] =
              __float2bfloat16(oacc[mf][n2][r]);
      }
    }
}

// ---------------- K3: output GEMM, bf16 MFMA, counted-vmcnt pipeline (R8) ----------------
__global__ __launch_bounds__(256) void k_out_mfma(
    const __hip_bfloat16* __restrict__ ab, const __hip_bfloat16* __restrict__ wot,
    const int* __restrict__ lutw, const int* __restrict__ luto,
    const float* __restrict__ bias, float* __restrict__ out) {
  __shared__ __align__(16) short As[2][128 * 64];
  __shared__ __align__(16) short Bs[2][128 * 64];
  const int tid = threadIdx.x;
  const int lid = blockIdx.x;                 // 3136 blocks
  const int wid = (lid & 7) * 392 + (lid >> 3);
  const int t0 = (wid >> 2) * 128;
  const int n0 = (wid & 3) * 128;
  const int lane = tid & 63, wave = tid >> 6;
  const int wm = wave >> 1, wn = wave & 1;

  size_t aoff[4];
  const __hip_bfloat16* bsrc[4];
#pragma unroll
  for (int s = 0; s < 4; ++s) {
    int c = s * 256 + tid;
    int row = c >> 3, kc = c & 7;
    aoff[s] = (size_t)lutw[t0 + row] + (size_t)(kc >> 2) * HEAD_STRIDE + (kc & 3) * 8;
    bsrc[s] = wot + (size_t)(n0 + row) * 512 + kc * 8;
  }

  f32x4 acc[4][4] = {};
  const int arow = wm * 64 + (lane & 15);
  const int brow = wn * 64 + (lane & 15);
  const int koff = (lane >> 4) * 8;
  const int sw = (lane & 7) << 3;

  // prologue: stage K-tile 0 into buf 0
#pragma unroll
  for (int s = 0; s < 4; ++s) {
    gload_lds16(ab + aoff[s], (char*)As[0] + wave * 1024 + s * 4096);
    gload_lds16(bsrc[s], (char*)Bs[0] + wave * 1024 + s * 4096);
  }

  for (int t = 0; t < 8; ++t) {
    const int buf = t & 1;
    if (t < 7) {
      const int kt = (t + 1) * 64;
      size_t hoff = (size_t)(kt >> 5) * HEAD_STRIDE;
#pragma unroll
      for (int s = 0; s < 4; ++s) {
        gload_lds16(ab + aoff[s] + hoff, (char*)As[buf ^ 1] + wave * 1024 + s * 4096);
        gload_lds16(bsrc[s] + kt, (char*)Bs[buf ^ 1] + wave * 1024 + s * 4096);
      }
      asm volatile("s_waitcnt vmcnt(8)" ::: "memory");
    } else {
      asm volatile("s_waitcnt vmcnt(0)" ::: "memory");
    }
    __builtin_amdgcn_s_barrier();
    __builtin_amdgcn_sched_barrier(0);

    bf16x8 af[2][4], bfr[2][4];
#pragma unroll
    for (int kk = 0; kk < 2; ++kk) {
      const int eo = kk * 32 + koff;
#pragma unroll
      for (int mf = 0; mf < 4; ++mf)
        af[kk][mf] = *(const bf16x8*)&As[buf][(arow + mf * 16) * 64 + eo];
#pragma unroll
      for (int nf = 0; nf < 4; ++nf)
        bfr[kk][nf] = *(const bf16x8*)&Bs[buf][(brow + nf * 16) * 64 + (eo ^ sw)];
    }
    __builtin_amdgcn_s_setprio(1);
#pragma unroll
    for (int kk = 0; kk < 2; ++kk)
#pragma unroll
      for (int mf = 0; mf < 4; ++mf)
#pragma unroll
        for (int nf = 0; nf < 4; ++nf)
          acc[mf][nf] = __builtin_amdgcn_mfma_f32_16x16x32_bf16(
              af[kk][mf], bfr[kk][nf], acc[mf][nf], 0, 0, 0);
    __builtin_amdgcn_s_setprio(0);
    __builtin_amdgcn_s_barrier();
    __builtin_amdgcn_sched_barrier(0);
  }

  float bia[4];
#pragma unroll
  for (int nf = 0; nf < 4; ++nf)
    bia[nf] = bias[n0 + wn * 64 + nf * 16 + (lane & 15)];

  const int tbase = t0 + wm * 64 + (lane >> 4) * 4;
  int ooff[4][4];
#pragma unroll
  for (int mf = 0; mf < 4; ++mf)
#pragma unroll
    for (int r = 0; r < 4; ++r)
      ooff[mf][r] = luto[tbase + mf * 16 + r];
#pragma unroll
  for (int mf = 0; mf < 4; ++mf) {
#pragma unroll
    for (int r = 0; r < 4; ++r) {
      float* op = out + (size_t)ooff[mf][r] + n0 + wn * 64 + (lane & 15);
#pragma unroll
      for (int nf = 0; nf < 4; ++nf) op[nf * 16] = acc[mf][nf][r] + bia[nf];
    }
  }
}

extern "C" void kernel_launch(void* const* d_in, const int* in_sizes, int n_in,
                              void* d_out, int out_size, void* d_ws, size_t ws_size,
                              hipStream_t stream) {
  const float* x     = (const float*)d_in[0];
  const float* w_qkv = (const float*)d_in[1];
  const float* pe    = (const float*)d_in[2];
  const float* w_out = (const float*)d_in[3];
  const float* b_out = (const float*)d_in[4];
  float* out = (float*)d_out;

  __hip_bfloat16* qb  = (__hip_bfloat16*)d_ws;          // 51,380,224
  __hip_bfloat16* kb  = qb + (size_t)QKV_ELEMS;         // 51,380,224
  __hip_bfloat16* vb  = kb + (size_t)QKV_ELEMS;         // 51,380,224
  __hip_bfloat16* xb  = vb + (size_t)QKV_ELEMS;         // 51,380,224 (aliased ab)
  __hip_bfloat16* ab  = xb;
  __hip_bfloat16* wbt = xb + (size_t)QKV_ELEMS;         // 786,432
  __hip_bfloat16* wot = wbt + (size_t)(1536 * 512);     // 262,144
  float* biasT = (float*)(wot + (size_t)(512 * 512));   // 262,144 f32 (1 MB)
  int* lutw = (int*)(biasT + 262144);                   // 100,352 int
  int* luto = lutw + NTOKENS;                           // 100,352 int

  k_preps<<<dim3(26760), dim3(256), 0, stream>>>(x, w_qkv, pe, w_out,
                                                 xb, wbt, wot, biasT, lutw, luto);
  k_qkv_mfma<<<dim3(9408), dim3(256), 0, stream>>>(xb, wbt, lutw, qb, kb, vb);
  k_attn_mfma<<<dim3(8192), dim3(256), 0, stream>>>(qb, kb, vb, biasT, ab);
  k_out_mfma<<<dim3(3136), dim3(256), 0, stream>>>(ab, wot, lutw, luto, b_out, out);
}